// Round 7
// baseline (209.667 us; speedup 1.0000x reference)
//
#include <hip/hip_runtime.h>
#include <hip/hip_bf16.h>
#include <stdint.h>

#define HD   256
#define SEQ  4096
#define NB   4
#define NTOK (NB * SEQ)
#define NEL  ((size_t)NTOK * HD)

typedef __hip_bfloat16 bf16;
typedef short    bf16x8  __attribute__((ext_vector_type(8)));
typedef float    f32x16  __attribute__((ext_vector_type(16)));
typedef float    f32x4_t __attribute__((ext_vector_type(4)));
typedef uint32_t u32x2_t __attribute__((ext_vector_type(2)));

// round-half-up f32->bf16
__device__ __forceinline__ uint32_t pk2bf(float a, float b) {
  uint32_t ua = __builtin_bit_cast(uint32_t, a);
  uint32_t ub = __builtin_bit_cast(uint32_t, b);
  return ((ua + 0x8000u) >> 16) | ((ub + 0x8000u) & 0xFFFF0000u);
}
__device__ __forceinline__ uint16_t f2bf(float a) {
  uint32_t u = __builtin_bit_cast(uint32_t, a);
  return (uint16_t)((u + 0x8000u) >> 16);
}
__device__ __forceinline__ float bf2f(short s) {
  return __builtin_bit_cast(float, ((uint32_t)(uint16_t)s) << 16);
}

// ---------------- fused QKV projection; which==2 (V) writes TRANSPOSED V_t directly
__global__ __launch_bounds__(256, 2) void proj_kernel(
    const float* __restrict__ Xq, const float* __restrict__ Xk, const float* __restrict__ Xv,
    const float* __restrict__ Wq, const float* __restrict__ Wk, const float* __restrict__ Wv,
    const float* __restrict__ bq, const float* __restrict__ bk, const float* __restrict__ bv,
    bf16* __restrict__ out0, float cexp) {
  const int which = (int)blockIdx.y;
  const float* X    = which == 0 ? Xq : which == 1 ? Xk : Xv;
  const float* W    = which == 0 ? Wq : which == 1 ? Wk : Wv;
  const float* bias = which == 0 ? bq : which == 1 ? bk : bv;
  const float scale = which == 0 ? cexp : 1.0f;

  __shared__ __align__(16) char praw[36864];  // xl[64][264] (34KB) or lt[256][72] (36KB)
  bf16 (*xl)[264] = (bf16(*)[264])praw;

  const int tid = (int)threadIdx.x;
  const int w = tid >> 6, l = tid & 63;
  const int m = l & 31, h = l >> 5;
  const int m0 = (int)blockIdx.x * 64;

#pragma unroll
  for (int j = 0; j < 16; ++j) {
    int e = j * 256 + tid;
    int row = e >> 6, c4 = e & 63;
    f32x4_t v = *(const f32x4_t*)(X + (size_t)(m0 + row) * HD + c4 * 4);
    u32x2_t pk; pk.x = pk2bf(v.x, v.y); pk.y = pk2bf(v.z, v.w);
    *(u32x2_t*)(&xl[row][c4 * 4]) = pk;
  }
  __syncthreads();

  f32x16 acc00 = {}, acc01 = {}, acc10 = {}, acc11 = {};

#pragma unroll
  for (int kh = 0; kh < 2; ++kh) {
    bf16x8 bfr[2][8];
#pragma unroll
    for (int nt2 = 0; nt2 < 2; ++nt2)
#pragma unroll
      for (int ks = 0; ks < 8; ++ks) {
        const float* wp = W + (size_t)(w * 64 + nt2 * 32 + m) * HD + (kh * 8 + ks) * 16 + h * 8;
        f32x4_t w0 = *(const f32x4_t*)wp;
        f32x4_t w1 = *(const f32x4_t*)(wp + 4);
        union { uint32_t u[4]; bf16x8 v; } cv;
        cv.u[0] = pk2bf(w0.x, w0.y); cv.u[1] = pk2bf(w0.z, w0.w);
        cv.u[2] = pk2bf(w1.x, w1.y); cv.u[3] = pk2bf(w1.z, w1.w);
        bfr[nt2][ks] = cv.v;
      }
#pragma unroll
    for (int ks = 0; ks < 8; ++ks) {
      int kbyte = (kh * 8 + ks) * 32 + h * 16;
      bf16x8 a0 = *(const bf16x8*)((const char*)&xl[m][0] + kbyte);
      bf16x8 a1 = *(const bf16x8*)((const char*)&xl[32 + m][0] + kbyte);
      acc00 = __builtin_amdgcn_mfma_f32_32x32x16_bf16(a0, bfr[0][ks], acc00, 0, 0, 0);
      acc01 = __builtin_amdgcn_mfma_f32_32x32x16_bf16(a0, bfr[1][ks], acc01, 0, 0, 0);
      acc10 = __builtin_amdgcn_mfma_f32_32x32x16_bf16(a1, bfr[0][ks], acc10, 0, 0, 0);
      acc11 = __builtin_amdgcn_mfma_f32_32x32x16_bf16(a1, bfr[1][ks], acc11, 0, 0, 0);
    }
  }
  __syncthreads();  // all waves done reading xl

  float bv0 = bias[w * 64 + m];
  float bv1 = bias[w * 64 + 32 + m];

  if (which == 2) {
    // V: write transposed. acc regs: lane owns col n (fixed), chunk r2 = 4 consecutive tokens.
    bf16 (*lt)[72] = (bf16(*)[72])praw;  // [n 256][token 72 pad]
    const int n0 = w * 64 + m;
#pragma unroll
    for (int r2 = 0; r2 < 4; ++r2) {
      int tok = 8 * r2 + 4 * h;
      u32x2_t v0, v1, v2, v3;
      v0.x = pk2bf(acc00[r2 * 4 + 0] + bv0, acc00[r2 * 4 + 1] + bv0);
      v0.y = pk2bf(acc00[r2 * 4 + 2] + bv0, acc00[r2 * 4 + 3] + bv0);
      v1.x = pk2bf(acc01[r2 * 4 + 0] + bv1, acc01[r2 * 4 + 1] + bv1);
      v1.y = pk2bf(acc01[r2 * 4 + 2] + bv1, acc01[r2 * 4 + 3] + bv1);
      v2.x = pk2bf(acc10[r2 * 4 + 0] + bv0, acc10[r2 * 4 + 1] + bv0);
      v2.y = pk2bf(acc10[r2 * 4 + 2] + bv0, acc10[r2 * 4 + 3] + bv0);
      v3.x = pk2bf(acc11[r2 * 4 + 0] + bv1, acc11[r2 * 4 + 1] + bv1);
      v3.y = pk2bf(acc11[r2 * 4 + 2] + bv1, acc11[r2 * 4 + 3] + bv1);
      *(u32x2_t*)&lt[n0][tok]            = v0;
      *(u32x2_t*)&lt[n0 + 32][tok]       = v1;
      *(u32x2_t*)&lt[n0][32 + tok]       = v2;
      *(u32x2_t*)&lt[n0 + 32][32 + tok]  = v3;
    }
    __syncthreads();
    bf16* Vt = out0 + 2 * NEL;
    const int batch = m0 >> 12, sg = m0 & (SEQ - 1);
#pragma unroll
    for (int j = 0; j < 8; ++j) {
      int unit = j * 256 + tid;  // 2048 units: 256 n-rows x 8 x 16B
      int r = unit >> 3, c = unit & 7;
      f32x4_t vv = *(const f32x4_t*)&lt[r][c * 8];
      *(f32x4_t*)(Vt + (size_t)batch * HD * SEQ + (size_t)r * SEQ + sg + c * 8) = vv;
    }
  } else {
    bf16* out = out0 + (size_t)which * NEL;
#pragma unroll
    for (int r = 0; r < 16; ++r) {
      int row = (r & 3) + ((r >> 2) << 3) + 4 * h;
      xl[row][w * 64 + m]           = __builtin_bit_cast(bf16, f2bf((acc00[r] + bv0) * scale));
      xl[row][w * 64 + 32 + m]      = __builtin_bit_cast(bf16, f2bf((acc01[r] + bv1) * scale));
      xl[32 + row][w * 64 + m]      = __builtin_bit_cast(bf16, f2bf((acc10[r] + bv0) * scale));
      xl[32 + row][w * 64 + 32 + m] = __builtin_bit_cast(bf16, f2bf((acc11[r] + bv1) * scale));
    }
    __syncthreads();
#pragma unroll
    for (int j = 0; j < 8; ++j) {
      int unit = j * 256 + tid;
      int row = unit >> 5, uc = unit & 31;
      f32x4_t vv = *(const f32x4_t*)((const char*)&xl[row][0] + uc * 16);
      *(f32x4_t*)(out + (size_t)(m0 + row) * HD + uc * 8) = vv;
    }
  }
}

// ---------------- attention: K direct global->reg (L1-served), V via LDS;
//                  QK+softmax hides V staging (T14 shape)
__global__ __launch_bounds__(256, 2) void attn_kernel(
    const bf16* __restrict__ Qp, const bf16* __restrict__ Kp,
    const bf16* __restrict__ Vt, bf16* __restrict__ Op,
    float* __restrict__ Lp, int kvlen, int cpx) {
  __shared__ __align__(128) char smem[65536];  // V dbuf 32K in [0,32K); epilogue uses all
  char* Vl = smem;

  const int tid = (int)threadIdx.x;
  const int w = tid >> 6, l = tid & 63;  // w = q-group (32 q rows)
  const int m = l & 31, h = l >> 5;

  // XCD-aware swizzle: 32 qt-blocks sharing a (b,sp) K/V panel land on one XCD
  int fid = (int)blockIdx.x + 32 * ((int)blockIdx.y + 4 * (int)blockIdx.z);
  int nid = (fid & 7) * cpx + (fid >> 3);
  const int qt = nid & 31, b = (nid >> 5) & 3, sp = nid >> 7;
  const int kvbase = sp * kvlen;
  const int niter = kvlen >> 5;

  // Q fragments (B-operand of swapped QK); Q pre-scaled by log2(e)/sqrt(H)
  const int gq = b * SEQ + qt * 128 + w * 32 + m;
  bf16x8 qf[16];
#pragma unroll
  for (int ks = 0; ks < 16; ++ks)
    qf[ks] = *(const bf16x8*)(Qp + (size_t)gq * HD + ks * 16 + h * 8);

  // K direct-load pointer: lane (m,h) reads row kv0+m, 16B chunk ks (imm offset ks*32B)
  const bf16* kptr = Kp + ((size_t)(b * SEQ + kvbase + m)) * HD + h * 8;

  f32x16 oacc[8] = {};  // O^T[d 256][q 32]
  float Lacc = 0.f;

  // V staging: 4 global_load_lds per wave -> vmcnt(4) = "previous stage landed"
  auto stage_V = [&](int buf, int kv0) {
#pragma unroll
    for (int i = 0; i < 4; ++i) {  // V: 64 rows x 256B (16 x 16B slots), quad-d per row
      int r = i * 16 + w * 4 + (l >> 4);
      int x = (l & 15) ^ (r & 15);
      int d = (r << 2) + (x >> 2), j = x & 3;
      const bf16* src = Vt + (size_t)b * HD * SEQ + (size_t)d * SEQ + kv0 + j * 8;
      __builtin_amdgcn_global_load_lds(
          (const __attribute__((address_space(1))) void*)src,
          (__attribute__((address_space(3))) void*)(Vl + buf * 16384 + i * 4096 + w * 1024),
          16, 0, 0);
    }
  };

  stage_V(0, kvbase);

  for (int t = 0; t < niter; ++t) {
    const int cur = t & 1;

    // barrier 1: all waves done with PV(t-1) -> safe to overwrite V buf (t+1)&1
    asm volatile("s_barrier" ::: "memory");
    if (t + 1 < niter) stage_V(cur ^ 1, kvbase + (t + 1) * 32);

    // QK(t): K fragments straight from global (L1-hit after first wave touches tile).
    // No LDS dependency -> overlaps the V staging latency above.
    f32x16 s0 = {};
    __builtin_amdgcn_s_setprio(1);
#pragma unroll
    for (int ks = 0; ks < 16; ++ks) {
      bf16x8 k0 = *(const bf16x8*)(kptr + ks * 16);
      s0 = __builtin_amdgcn_mfma_f32_32x32x16_bf16(k0, qf[ks], s0, 0, 0, 0);
    }
    __builtin_amdgcn_s_setprio(0);
    kptr += 32 * HD;  // next KV tile

    // no-max softmax (Q pre-scaled): p = exp2(S')
    float p[16];
#pragma unroll
    for (int r = 0; r < 16; ++r) p[r] = __builtin_exp2f(s0[r]);
    float ls = 0.f;
#pragma unroll
    for (int r = 0; r < 16; ++r) ls += p[r];
    Lacc += ls;

    // P b-frags: cvt_pk to bf16 pairs, permlane32_swap fills other half's residues
    bf16x8 pf[2];
#pragma unroll
    for (int ks = 0; ks < 2; ++ks) {
      int o = ks * 8;
      uint32_t P0, P1, P2, P3;
      asm("v_cvt_pk_bf16_f32 %0, %1, %2" : "=v"(P0) : "v"(p[o + 0]), "v"(p[o + 1]));
      asm("v_cvt_pk_bf16_f32 %0, %1, %2" : "=v"(P1) : "v"(p[o + 2]), "v"(p[o + 3]));
      asm("v_cvt_pk_bf16_f32 %0, %1, %2" : "=v"(P2) : "v"(p[o + 4]), "v"(p[o + 5]));
      asm("v_cvt_pk_bf16_f32 %0, %1, %2" : "=v"(P3) : "v"(p[o + 6]), "v"(p[o + 7]));
      asm volatile("v_permlane32_swap_b32 %0, %1" : "+v"(P0), "+v"(P2));
      asm volatile("v_permlane32_swap_b32 %0, %1" : "+v"(P1), "+v"(P3));
      union { uint32_t u[4]; bf16x8 v; } cv;
      cv.u[0] = P0; cv.u[1] = P1; cv.u[2] = P2; cv.u[3] = P3;
      pf[ks] = cv.v;
    }

    // V(t) must be in LDS block-wide: only the 4 newest loads (V t+1) may stay in flight
    if (t + 1 < niter) {
      asm volatile("s_waitcnt vmcnt(4)" ::: "memory");
    } else {
      asm volatile("s_waitcnt vmcnt(0)" ::: "memory");
    }
    asm volatile("s_barrier" ::: "memory");

    // O^T[d][q] += V_t[d][kk] * P[q][kk], full D=256, kk=32
    const char* vb = Vl + cur * 16384;
    __builtin_amdgcn_s_setprio(1);
#pragma unroll
    for (int dt = 0; dt < 8; ++dt) {
      int d = dt * 32 + m;
      int r = d >> 2;
#pragma unroll
      for (int ks = 0; ks < 2; ++ks) {
        int x = (((d & 3) << 2) | (2 * ks + h)) ^ (r & 15);
        bf16x8 vf = *(const bf16x8*)(vb + r * 256 + x * 16);
        oacc[dt] = __builtin_amdgcn_mfma_f32_32x32x16_bf16(vf, pf[ks], oacc[dt], 0, 0, 0);
      }
    }
    __builtin_amdgcn_s_setprio(0);
  }

  // L for this sp (h halves combined in-wave; each wave owns full kk)
  float Lrow = Lacc + __shfl_xor(Lacc, 32, 64);
  if (l < 32)
    Lp[(size_t)sp * NTOK + b * SEQ + qt * 128 + w * 32 + m] = Lrow;

  // transpose writeout in two 64-q halves; pack bf16 partials
#pragma unroll
  for (int half = 0; half < 2; ++half) {
    __syncthreads();
    if ((w >> 1) == half) {
      const int ql = (w & 1) * 32 + m;  // 0..63
#pragma unroll
      for (int dt = 0; dt < 8; ++dt)
#pragma unroll
        for (int rq = 0; rq < 4; ++rq) {
          int drow = dt * 32 + rq * 8 + 4 * h;
          f32x4_t vv;
          vv.x = oacc[dt][rq * 4 + 0]; vv.y = oacc[dt][rq * 4 + 1];
          vv.z = oacc[dt][rq * 4 + 2]; vv.w = oacc[dt][rq * 4 + 3];
          int slot = (drow >> 2) ^ (ql & 31);
          *(f32x4_t*)(smem + ql * 1024 + slot * 16) = vv;
        }
    }
    __syncthreads();
#pragma unroll
    for (int j = 0; j < 16; ++j) {
      int unit = j * 256 + tid;
      int qq = unit >> 6, sl = unit & 63;
      f32x4_t vv = *(const f32x4_t*)(smem + qq * 1024 + ((sl ^ (qq & 31)) << 4));
      u32x2_t pk; pk.x = pk2bf(vv.x, vv.y); pk.y = pk2bf(vv.z, vv.w);
      int gqq = b * SEQ + qt * 128 + half * 64 + qq;
      *(u32x2_t*)(Op + (size_t)sp * NEL + (size_t)gqq * HD + sl * 4) = pk;
    }
  }
}

// ---------------- combine bf16 partials: out = sum(O_sp) / sum(L_sp), f32 out
__global__ __launch_bounds__(256, 2) void combine_kernel(
    const bf16* __restrict__ Op, const float* __restrict__ Lp,
    float* __restrict__ out, int nsplit) {
  size_t u = (size_t)blockIdx.x * 256 + threadIdx.x;  // 8-elem units
  int row = (int)(u >> 5);
  float a[8] = {};
  float Ls = 0.f;
  for (int s = 0; s < nsplit; ++s) {
    bf16x8 pv = ((const bf16x8*)Op)[u + (size_t)s * (NEL >> 3)];
#pragma unroll
    for (int i = 0; i < 8; ++i) a[i] += bf2f(pv[i]);
    Ls += Lp[(size_t)s * NTOK + row];
  }
  float inv = 1.f / Ls;
  f32x4_t lo, hi;
  lo.x = a[0] * inv; lo.y = a[1] * inv; lo.z = a[2] * inv; lo.w = a[3] * inv;
  hi.x = a[4] * inv; hi.y = a[5] * inv; hi.z = a[6] * inv; hi.w = a[7] * inv;
  ((f32x4_t*)out)[2 * u]     = lo;
  ((f32x4_t*)out)[2 * u + 1] = hi;
}

extern "C" void kernel_launch(void* const* d_in, const int* in_sizes, int n_in,
                              void* d_out, int out_size, void* d_ws, size_t ws_size,
                              hipStream_t stream) {
  (void)in_sizes; (void)n_in; (void)out_size;
  const float* q  = (const float*)d_in[0];
  const float* k  = (const float*)d_in[1];
  const float* v  = (const float*)d_in[2];
  const float* Wq = (const float*)d_in[3];
  const float* bq = (const float*)d_in[4];
  const float* Wk = (const float*)d_in[5];
  const float* bk = (const float*)d_in[6];
  const float* Wv = (const float*)d_in[7];
  const float* bv = (const float*)d_in[8];

  char* ws = (char*)d_ws;
  bf16* Qp  = (bf16*)ws;          // proj grid.y: 0->Qp, 1->Kp, 2->Vt (transposed)
  bf16* Kp  = Qp + NEL;
  bf16* Vt  = Qp + 2 * NEL;
  bf16* Opb = Qp + 3 * NEL;       // bf16 partials [nsplit][NTOK][HD]

  // pick largest KV split that fits the workspace: 4 -> 2 -> 1
  int nsplit = 1;
  for (int cand = 4; cand > 1; cand >>= 1) {
    size_t need = 3 * NEL * 2 + (size_t)cand * NEL * 2 + (size_t)cand * NTOK * 4;
    if (ws_size >= need) { nsplit = cand; break; }
  }
  float* Lp = (float*)(Opb + (size_t)nsplit * NEL);

  const float CEXP = 0.09016844f;  // log2(e) / sqrt(256), folded into Q projection

  proj_kernel<<<dim3(NTOK / 64, 3), 256, 0, stream>>>(q, k, v, Wq, Wk, Wv, bq, bk, bv, Qp, CEXP);
  attn_kernel<<<dim3(SEQ / 128, NB, nsplit), 256, 0, stream>>>(
      Qp, Kp, Vt, Opb, Lp, SEQ / nsplit, 16 * nsplit);
  combine_kernel<<<(int)(NEL / 8 / 256), 256, 0, stream>>>(Opb, Lp, (float*)d_out, nsplit);
}

// Round 8
// 123.938 us; speedup vs baseline: 1.6917x; 1.6917x over previous
//
#include <hip/hip_runtime.h>
#include <hip/hip_bf16.h>
#include <stdint.h>

#define HD   256
#define SEQ  4096
#define NB   4
#define NTOK (NB * SEQ)
#define NEL  ((size_t)NTOK * HD)

typedef __hip_bfloat16 bf16;
typedef short    bf16x8  __attribute__((ext_vector_type(8)));
typedef float    f32x16  __attribute__((ext_vector_type(16)));
typedef float    f32x4_t __attribute__((ext_vector_type(4)));
typedef uint32_t u32x2_t __attribute__((ext_vector_type(2)));

// round-half-up f32->bf16
__device__ __forceinline__ uint32_t pk2bf(float a, float b) {
  uint32_t ua = __builtin_bit_cast(uint32_t, a);
  uint32_t ub = __builtin_bit_cast(uint32_t, b);
  return ((ua + 0x8000u) >> 16) | ((ub + 0x8000u) & 0xFFFF0000u);
}
__device__ __forceinline__ uint16_t f2bf(float a) {
  uint32_t u = __builtin_bit_cast(uint32_t, a);
  return (uint16_t)((u + 0x8000u) >> 16);
}
__device__ __forceinline__ float bf2f(short s) {
  return __builtin_bit_cast(float, ((uint32_t)(uint16_t)s) << 16);
}

// ---------------- fused QKV projection; which==2 (V) writes TRANSPOSED V_t directly
__global__ __launch_bounds__(256, 2) void proj_kernel(
    const float* __restrict__ Xq, const float* __restrict__ Xk, const float* __restrict__ Xv,
    const float* __restrict__ Wq, const float* __restrict__ Wk, const float* __restrict__ Wv,
    const float* __restrict__ bq, const float* __restrict__ bk, const float* __restrict__ bv,
    bf16* __restrict__ out0, float cexp) {
  const int which = (int)blockIdx.y;
  const float* X    = which == 0 ? Xq : which == 1 ? Xk : Xv;
  const float* W    = which == 0 ? Wq : which == 1 ? Wk : Wv;
  const float* bias = which == 0 ? bq : which == 1 ? bk : bv;
  const float scale = which == 0 ? cexp : 1.0f;

  __shared__ __align__(16) char praw[36864];  // xl[64][264] (34KB) or lt[256][72] (36KB)
  bf16 (*xl)[264] = (bf16(*)[264])praw;

  const int tid = (int)threadIdx.x;
  const int w = tid >> 6, l = tid & 63;
  const int m = l & 31, h = l >> 5;
  const int m0 = (int)blockIdx.x * 64;

#pragma unroll
  for (int j = 0; j < 16; ++j) {
    int e = j * 256 + tid;
    int row = e >> 6, c4 = e & 63;
    f32x4_t v = *(const f32x4_t*)(X + (size_t)(m0 + row) * HD + c4 * 4);
    u32x2_t pk; pk.x = pk2bf(v.x, v.y); pk.y = pk2bf(v.z, v.w);
    *(u32x2_t*)(&xl[row][c4 * 4]) = pk;
  }
  __syncthreads();

  f32x16 acc00 = {}, acc01 = {}, acc10 = {}, acc11 = {};

#pragma unroll
  for (int kh = 0; kh < 2; ++kh) {
    bf16x8 bfr[2][8];
#pragma unroll
    for (int nt2 = 0; nt2 < 2; ++nt2)
#pragma unroll
      for (int ks = 0; ks < 8; ++ks) {
        const float* wp = W + (size_t)(w * 64 + nt2 * 32 + m) * HD + (kh * 8 + ks) * 16 + h * 8;
        f32x4_t w0 = *(const f32x4_t*)wp;
        f32x4_t w1 = *(const f32x4_t*)(wp + 4);
        union { uint32_t u[4]; bf16x8 v; } cv;
        cv.u[0] = pk2bf(w0.x, w0.y); cv.u[1] = pk2bf(w0.z, w0.w);
        cv.u[2] = pk2bf(w1.x, w1.y); cv.u[3] = pk2bf(w1.z, w1.w);
        bfr[nt2][ks] = cv.v;
      }
#pragma unroll
    for (int ks = 0; ks < 8; ++ks) {
      int kbyte = (kh * 8 + ks) * 32 + h * 16;
      bf16x8 a0 = *(const bf16x8*)((const char*)&xl[m][0] + kbyte);
      bf16x8 a1 = *(const bf16x8*)((const char*)&xl[32 + m][0] + kbyte);
      acc00 = __builtin_amdgcn_mfma_f32_32x32x16_bf16(a0, bfr[0][ks], acc00, 0, 0, 0);
      acc01 = __builtin_amdgcn_mfma_f32_32x32x16_bf16(a0, bfr[1][ks], acc01, 0, 0, 0);
      acc10 = __builtin_amdgcn_mfma_f32_32x32x16_bf16(a1, bfr[0][ks], acc10, 0, 0, 0);
      acc11 = __builtin_amdgcn_mfma_f32_32x32x16_bf16(a1, bfr[1][ks], acc11, 0, 0, 0);
    }
  }
  __syncthreads();  // all waves done reading xl

  float bv0 = bias[w * 64 + m];
  float bv1 = bias[w * 64 + 32 + m];

  if (which == 2) {
    // V: write transposed. acc regs: lane owns col n (fixed), chunk r2 = 4 consecutive tokens.
    bf16 (*lt)[72] = (bf16(*)[72])praw;  // [n 256][token 72 pad]
    const int n0 = w * 64 + m;
#pragma unroll
    for (int r2 = 0; r2 < 4; ++r2) {
      int tok = 8 * r2 + 4 * h;
      u32x2_t v0, v1, v2, v3;
      v0.x = pk2bf(acc00[r2 * 4 + 0] + bv0, acc00[r2 * 4 + 1] + bv0);
      v0.y = pk2bf(acc00[r2 * 4 + 2] + bv0, acc00[r2 * 4 + 3] + bv0);
      v1.x = pk2bf(acc01[r2 * 4 + 0] + bv1, acc01[r2 * 4 + 1] + bv1);
      v1.y = pk2bf(acc01[r2 * 4 + 2] + bv1, acc01[r2 * 4 + 3] + bv1);
      v2.x = pk2bf(acc10[r2 * 4 + 0] + bv0, acc10[r2 * 4 + 1] + bv0);
      v2.y = pk2bf(acc10[r2 * 4 + 2] + bv0, acc10[r2 * 4 + 3] + bv0);
      v3.x = pk2bf(acc11[r2 * 4 + 0] + bv1, acc11[r2 * 4 + 1] + bv1);
      v3.y = pk2bf(acc11[r2 * 4 + 2] + bv1, acc11[r2 * 4 + 3] + bv1);
      *(u32x2_t*)&lt[n0][tok]            = v0;
      *(u32x2_t*)&lt[n0 + 32][tok]       = v1;
      *(u32x2_t*)&lt[n0][32 + tok]       = v2;
      *(u32x2_t*)&lt[n0 + 32][32 + tok]  = v3;
    }
    __syncthreads();
    bf16* Vt = out0 + 2 * NEL;
    const int batch = m0 >> 12, sg = m0 & (SEQ - 1);
#pragma unroll
    for (int j = 0; j < 8; ++j) {
      int unit = j * 256 + tid;  // 2048 units: 256 n-rows x 8 x 16B
      int r = unit >> 3, c = unit & 7;
      f32x4_t vv = *(const f32x4_t*)&lt[r][c * 8];
      *(f32x4_t*)(Vt + (size_t)batch * HD * SEQ + (size_t)r * SEQ + sg + c * 8) = vv;
    }
  } else {
    bf16* out = out0 + (size_t)which * NEL;
#pragma unroll
    for (int r = 0; r < 16; ++r) {
      int row = (r & 3) + ((r >> 2) << 3) + 4 * h;
      xl[row][w * 64 + m]           = __builtin_bit_cast(bf16, f2bf((acc00[r] + bv0) * scale));
      xl[row][w * 64 + 32 + m]      = __builtin_bit_cast(bf16, f2bf((acc01[r] + bv1) * scale));
      xl[32 + row][w * 64 + m]      = __builtin_bit_cast(bf16, f2bf((acc10[r] + bv0) * scale));
      xl[32 + row][w * 64 + 32 + m] = __builtin_bit_cast(bf16, f2bf((acc11[r] + bv1) * scale));
    }
    __syncthreads();
#pragma unroll
    for (int j = 0; j < 8; ++j) {
      int unit = j * 256 + tid;
      int row = unit >> 5, uc = unit & 31;
      f32x4_t vv = *(const f32x4_t*)((const char*)&xl[row][0] + uc * 16);
      *(f32x4_t*)(out + (size_t)(m0 + row) * HD + uc * 8) = vv;
    }
  }
}

// ---------------- attention: QBLK=256 (8 waves), KVBLK=32, K+V LDS dbuf, counted vmcnt
__global__ __launch_bounds__(512, 2) void attn_kernel(
    const bf16* __restrict__ Qp, const bf16* __restrict__ Kp,
    const bf16* __restrict__ Vt, bf16* __restrict__ Op,
    float* __restrict__ Lp, int kvlen, int cpx) {
  __shared__ __align__(128) char smem[65536];  // K dbuf 32K | V dbuf 32K; reused in epilogue
  char* Kl = smem;
  char* Vl = smem + 32768;

  const int tid = (int)threadIdx.x;
  const int w = tid >> 6, l = tid & 63;  // w = q-group (32 q rows), 8 groups
  const int m = l & 31, h = l >> 5;

  // XCD-aware swizzle: the 16 qt-blocks sharing a (b,sp) K/V panel land on one XCD
  int fid = (int)blockIdx.x + 16 * ((int)blockIdx.y + 4 * (int)blockIdx.z);
  int nid = (fid & 7) * cpx + (fid >> 3);
  const int qt = nid & 15, b = (nid >> 4) & 3, sp = nid >> 6;
  const int kvbase = sp * kvlen;
  const int niter = kvlen >> 5;

  // Q fragments (B-operand of swapped QK); Q pre-scaled by log2(e)/sqrt(H)
  const int gq = b * SEQ + qt * 256 + w * 32 + m;
  bf16x8 qf[16];
#pragma unroll
  for (int ks = 0; ks < 16; ++ks)
    qf[ks] = *(const bf16x8*)(Qp + (size_t)gq * HD + ks * 16 + h * 8);

  f32x16 oacc[8] = {};  // O^T[d 256][q 32]
  float Lacc = 0.f;

  // 4 global_load_lds per wave per stage (2 K + 2 V) -> vmcnt(4) = "previous stage landed"
  auto stage = [&](int buf, int kv0) {
#pragma unroll
    for (int i = 0; i < 2; ++i) {  // K: 32 rows x 512B (32 x 16B slots), XOR-swizzled source
      int kk = i * 16 + w * 2 + (l >> 5);
      int s = (l & 31) ^ (kk & 31);
      const bf16* src = Kp + (size_t)(b * SEQ + kv0 + kk) * HD + s * 8;
      __builtin_amdgcn_global_load_lds(
          (const __attribute__((address_space(1))) void*)src,
          (__attribute__((address_space(3))) void*)(Kl + buf * 16384 + i * 8192 + w * 1024),
          16, 0, 0);
    }
#pragma unroll
    for (int i = 0; i < 2; ++i) {  // V: 64 rows x 256B (16 x 16B slots), quad-d per row
      int r = i * 32 + w * 4 + (l >> 4);
      int x = (l & 15) ^ (r & 15);
      int d = (r << 2) + (x >> 2), j = x & 3;
      const bf16* src = Vt + (size_t)b * HD * SEQ + (size_t)d * SEQ + kv0 + j * 8;
      __builtin_amdgcn_global_load_lds(
          (const __attribute__((address_space(1))) void*)src,
          (__attribute__((address_space(3))) void*)(Vl + buf * 16384 + i * 8192 + w * 1024),
          16, 0, 0);
    }
  };

  stage(0, kvbase);

  for (int t = 0; t < niter; ++t) {
    const int cur = t & 1;

    // barrier 1: all waves finished compute(t-1) -> safe to overwrite buf cur^1
    asm volatile("s_barrier" ::: "memory");
    if (t + 1 < niter) {
      stage(cur ^ 1, kvbase + (t + 1) * 32);
      asm volatile("s_waitcnt vmcnt(4)" ::: "memory");  // stage(t) complete; t+1 in flight
    } else {
      asm volatile("s_waitcnt vmcnt(0)" ::: "memory");
    }
    // barrier 2: every wave's stage(t) data landed -> buf cur valid block-wide
    asm volatile("s_barrier" ::: "memory");

    // S^T[kk 32][q 32], contraction over H=256
    f32x16 s0 = {};
    const char* kb = Kl + cur * 16384 + m * 512;
    __builtin_amdgcn_s_setprio(1);
#pragma unroll
    for (int ks = 0; ks < 16; ++ks) {
      bf16x8 k0 = *(const bf16x8*)(kb + (((2 * ks + h) ^ m) << 4));
      s0 = __builtin_amdgcn_mfma_f32_32x32x16_bf16(k0, qf[ks], s0, 0, 0, 0);
    }
    __builtin_amdgcn_s_setprio(0);

    // no-max softmax (Q pre-scaled): p = exp2(S')
    float p[16];
#pragma unroll
    for (int r = 0; r < 16; ++r) p[r] = __builtin_exp2f(s0[r]);
    float ls = 0.f;
#pragma unroll
    for (int r = 0; r < 16; ++r) ls += p[r];
    Lacc += ls;

    // P b-frags: cvt_pk to bf16 pairs, permlane32_swap fills other half's residues
    bf16x8 pf[2];
#pragma unroll
    for (int ks = 0; ks < 2; ++ks) {
      int o = ks * 8;
      uint32_t P0, P1, P2, P3;
      asm("v_cvt_pk_bf16_f32 %0, %1, %2" : "=v"(P0) : "v"(p[o + 0]), "v"(p[o + 1]));
      asm("v_cvt_pk_bf16_f32 %0, %1, %2" : "=v"(P1) : "v"(p[o + 2]), "v"(p[o + 3]));
      asm("v_cvt_pk_bf16_f32 %0, %1, %2" : "=v"(P2) : "v"(p[o + 4]), "v"(p[o + 5]));
      asm("v_cvt_pk_bf16_f32 %0, %1, %2" : "=v"(P3) : "v"(p[o + 6]), "v"(p[o + 7]));
      asm volatile("v_permlane32_swap_b32 %0, %1" : "+v"(P0), "+v"(P2));
      asm volatile("v_permlane32_swap_b32 %0, %1" : "+v"(P1), "+v"(P3));
      union { uint32_t u[4]; bf16x8 v; } cv;
      cv.u[0] = P0; cv.u[1] = P1; cv.u[2] = P2; cv.u[3] = P3;
      pf[ks] = cv.v;
    }

    // O^T[d][q] += V_t[d][kk] * P[q][kk], full D=256, kk=32
    const char* vb = Vl + cur * 16384;
    __builtin_amdgcn_s_setprio(1);
#pragma unroll
    for (int dt = 0; dt < 8; ++dt) {
      int d = dt * 32 + m;
      int r = d >> 2;
#pragma unroll
      for (int ks = 0; ks < 2; ++ks) {
        int x = (((d & 3) << 2) | (2 * ks + h)) ^ (r & 15);
        bf16x8 vf = *(const bf16x8*)(vb + r * 256 + x * 16);
        oacc[dt] = __builtin_amdgcn_mfma_f32_32x32x16_bf16(vf, pf[ks], oacc[dt], 0, 0, 0);
      }
    }
    __builtin_amdgcn_s_setprio(0);
  }

  // L for this sp (h halves combined in-wave; each wave owns full kk)
  float Lrow = Lacc + __shfl_xor(Lacc, 32, 64);
  if (l < 32)
    Lp[(size_t)sp * NTOK + b * SEQ + qt * 256 + w * 32 + m] = Lrow;

  // transpose writeout in four 64-q rounds (waves 2r,2r+1 stage in round r); bf16 partials
#pragma unroll
  for (int half = 0; half < 4; ++half) {
    __syncthreads();
    if ((w >> 1) == half) {
      const int ql = (w & 1) * 32 + m;  // 0..63
#pragma unroll
      for (int dt = 0; dt < 8; ++dt)
#pragma unroll
        for (int rq = 0; rq < 4; ++rq) {
          int drow = dt * 32 + rq * 8 + 4 * h;
          f32x4_t vv;
          vv.x = oacc[dt][rq * 4 + 0]; vv.y = oacc[dt][rq * 4 + 1];
          vv.z = oacc[dt][rq * 4 + 2]; vv.w = oacc[dt][rq * 4 + 3];
          int slot = (drow >> 2) ^ (ql & 31);
          *(f32x4_t*)(smem + ql * 1024 + slot * 16) = vv;
        }
    }
    __syncthreads();
#pragma unroll
    for (int j = 0; j < 8; ++j) {
      int unit = j * 512 + tid;
      int qq = unit >> 6, sl = unit & 63;
      f32x4_t vv = *(const f32x4_t*)(smem + qq * 1024 + ((sl ^ (qq & 31)) << 4));
      u32x2_t pk; pk.x = pk2bf(vv.x, vv.y); pk.y = pk2bf(vv.z, vv.w);
      int gqq = b * SEQ + qt * 256 + half * 64 + qq;
      *(u32x2_t*)(Op + (size_t)sp * NEL + (size_t)gqq * HD + sl * 4) = pk;
    }
  }
}

// ---------------- combine bf16 partials: out = sum(O_sp) / sum(L_sp), f32 out
__global__ __launch_bounds__(256, 2) void combine_kernel(
    const bf16* __restrict__ Op, const float* __restrict__ Lp,
    float* __restrict__ out, int nsplit) {
  size_t u = (size_t)blockIdx.x * 256 + threadIdx.x;  // 8-elem units
  int row = (int)(u >> 5);
  float a[8] = {};
  float Ls = 0.f;
  for (int s = 0; s < nsplit; ++s) {
    bf16x8 pv = ((const bf16x8*)Op)[u + (size_t)s * (NEL >> 3)];
#pragma unroll
    for (int i = 0; i < 8; ++i) a[i] += bf2f(pv[i]);
    Ls += Lp[(size_t)s * NTOK + row];
  }
  float inv = 1.f / Ls;
  f32x4_t lo, hi;
  lo.x = a[0] * inv; lo.y = a[1] * inv; lo.z = a[2] * inv; lo.w = a[3] * inv;
  hi.x = a[4] * inv; hi.y = a[5] * inv; hi.z = a[6] * inv; hi.w = a[7] * inv;
  ((f32x4_t*)out)[2 * u]     = lo;
  ((f32x4_t*)out)[2 * u + 1] = hi;
}

extern "C" void kernel_launch(void* const* d_in, const int* in_sizes, int n_in,
                              void* d_out, int out_size, void* d_ws, size_t ws_size,
                              hipStream_t stream) {
  (void)in_sizes; (void)n_in; (void)out_size;
  const float* q  = (const float*)d_in[0];
  const float* k  = (const float*)d_in[1];
  const float* v  = (const float*)d_in[2];
  const float* Wq = (const float*)d_in[3];
  const float* bq = (const float*)d_in[4];
  const float* Wk = (const float*)d_in[5];
  const float* bk = (const float*)d_in[6];
  const float* Wv = (const float*)d_in[7];
  const float* bv = (const float*)d_in[8];

  char* ws = (char*)d_ws;
  bf16* Qp  = (bf16*)ws;          // proj grid.y: 0->Qp, 1->Kp, 2->Vt (transposed)
  bf16* Kp  = Qp + NEL;
  bf16* Vt  = Qp + 2 * NEL;
  bf16* Opb = Qp + 3 * NEL;       // bf16 partials [nsplit][NTOK][HD]

  // pick largest KV split that fits the workspace: 4 -> 2 -> 1
  int nsplit = 1;
  for (int cand = 4; cand > 1; cand >>= 1) {
    size_t need = 3 * NEL * 2 + (size_t)cand * NEL * 2 + (size_t)cand * NTOK * 4;
    if (ws_size >= need) { nsplit = cand; break; }
  }
  float* Lp = (float*)(Opb + (size_t)nsplit * NEL);

  const float CEXP = 0.09016844f;  // log2(e) / sqrt(256), folded into Q projection

  proj_kernel<<<dim3(NTOK / 64, 3), 256, 0, stream>>>(q, k, v, Wq, Wk, Wv, bq, bk, bv, Qp, CEXP);
  attn_kernel<<<dim3(SEQ / 256, NB, nsplit), 512, 0, stream>>>(
      Qp, Kp, Vt, Opb, Lp, SEQ / nsplit, 8 * nsplit);
  combine_kernel<<<(int)(NEL / 8 / 256), 256, 0, stream>>>(Opb, Lp, (float*)d_out, nsplit);
}